// Round 15
// baseline (77.993 us; speedup 1.0000x reference)
//
#include <hip/hip_runtime.h>

#define IN_CH 128
#define OUT_CH 64

#define CSHIFT 6                 // bucket = 64 dst nodes
#define BNODES 64
#define NCMAX 1024               // LDS counter bound (NC = 782 for N=50000)
#define NGRP 8                   // XCD groups: chunk = (bucket, blockIdx%8)
#define CAPC 256                 // per-chunk capacity (mean ~128, +11 sigma)
#define CAP 1536                 // scol LDS bound (bucket total mean ~1023)
#define BIN_EPT 8                // edges per thread in binning kernel

typedef __attribute__((ext_vector_type(8))) short bf16x8;
typedef __attribute__((ext_vector_type(4))) float f32x4;

__device__ inline unsigned short f2bf(float x) {      // RNE f32 -> bf16 bits
    unsigned int u = __builtin_bit_cast(unsigned int, x);
    return (unsigned short)((u + 0x7FFFu + ((u >> 16) & 1u)) >> 16);
}
__device__ inline float bf2f(unsigned short h) {
    unsigned int u = ((unsigned int)h) << 16;
    return __builtin_bit_cast(float, u);
}

// ---- 1. bin edges into per-(bucket, XCD-group) chunks, packed (dst<<16)|src ----
// group = blockIdx&7: only same-XCD blocks write a chunk -> L2 merges full
// lines -> no cross-XCD partial-line writebacks (the fill_csr pathology).
__global__ void bin_edges(const int* __restrict__ ei, int* __restrict__ gctr,
                          unsigned int* __restrict__ ebuf, int E, int NC) {
    __shared__ int cnt[NCMAX];
    __shared__ int gbase[NCMAX];
    const int g = blockIdx.x & (NGRP - 1);
    for (int i = threadIdx.x; i < NC; i += blockDim.x) cnt[i] = 0;
    __syncthreads();

    unsigned int pk[BIN_EPT];
    int bk[BIN_EPT];
    const int g0 = (blockIdx.x * blockDim.x + threadIdx.x) * BIN_EPT;

    if (g0 + BIN_EPT <= E) {
        int4 s0 = *(const int4*)(ei + g0);
        int4 s1 = *(const int4*)(ei + g0 + 4);
        int4 d0 = *(const int4*)(ei + E + g0);
        int4 d1 = *(const int4*)(ei + E + g0 + 4);
        int ss[BIN_EPT] = {s0.x, s0.y, s0.z, s0.w, s1.x, s1.y, s1.z, s1.w};
        int dd[BIN_EPT] = {d0.x, d0.y, d0.z, d0.w, d1.x, d1.y, d1.z, d1.w};
#pragma unroll
        for (int k = 0; k < BIN_EPT; ++k) {
            pk[k] = ((unsigned int)dd[k] << 16) | (unsigned int)ss[k];
            bk[k] = dd[k] >> CSHIFT;
            atomicAdd(&cnt[bk[k]], 1);
        }
    } else {
#pragma unroll
        for (int k = 0; k < BIN_EPT; ++k) {
            int e = g0 + k;
            if (e < E) {
                int s = ei[e];
                int d = ei[E + e];
                pk[k] = ((unsigned int)d << 16) | (unsigned int)s;
                bk[k] = d >> CSHIFT;
                atomicAdd(&cnt[bk[k]], 1);
            } else bk[k] = -1;
        }
    }
    __syncthreads();
    for (int i = threadIdx.x; i < NC; i += blockDim.x) {
        int c = cnt[i];
        gbase[i] = c ? atomicAdd(&gctr[i * NGRP + g], c) : 0;
    }
    __syncthreads();
    for (int i = threadIdx.x; i < NC; i += blockDim.x) cnt[i] = 0;  // reuse as local cursor
    __syncthreads();
#pragma unroll
    for (int k = 0; k < BIN_EPT; ++k) {
        if (bk[k] >= 0) {
            int o = gbase[bk[k]] + atomicAdd(&cnt[bk[k]], 1);
            if (o < CAPC)   // per-chunk overflow guard (statistically unreachable)
                ebuf[((size_t)bk[k] * NGRP + g) * CAPC + o] = pk[k];
        }
    }
}

// ---- 2. fused: degree->dinv + within-bucket exclusive offsets (blocks 0..NC-1),
//      W-fragment prep (block NC) ----
__global__ void degree_wfrag(const unsigned int* __restrict__ ebuf,
                             const int* __restrict__ gctr,
                             float* __restrict__ dinv, int* __restrict__ boff,
                             int N, int NC,
                             const float* __restrict__ W,
                             unsigned short* __restrict__ wf) {
    const int b = blockIdx.x;
    if (b == NC) {   // W fragment pre-pack: wf[((nt*4+kk)*64+lane)*8+j]
        for (int i = threadIdx.x; i < 4 * 4 * 64 * 8; i += blockDim.x) {
            int j    = i & 7;
            int lane = (i >> 3) & 63;
            int kk   = (i >> 9) & 3;
            int nt   = i >> 11;
            int k = kk * 32 + ((lane >> 4) & 3) * 8 + j;
            int n = nt * 16 + (lane & 15);
            wf[i] = f2bf(W[k * OUT_CH + n]);
        }
        return;
    }
    __shared__ int cnt[BNODES];
    __shared__ int off[BNODES];
    const int tid = threadIdx.x;
    const int n0 = b << CSHIFT;
    if (tid < BNODES) cnt[tid] = 0;
    __syncthreads();
#pragma unroll
    for (int gi = 0; gi < NGRP; ++gi) {
        const int ec = min(gctr[b * NGRP + gi], CAPC);
        const unsigned int* eb = ebuf + ((size_t)b * NGRP + gi) * CAPC;
        for (int i = tid; i < ec; i += blockDim.x)
            atomicAdd(&cnt[(int)(eb[i] >> 16) - n0], 1);
    }
    __syncthreads();
    if (tid < BNODES) off[tid] = cnt[tid];
    __syncthreads();
    for (int o = 1; o < BNODES; o <<= 1) {
        int v = 0;
        if (tid < BNODES && tid >= o) v = off[tid - o];
        __syncthreads();
        if (tid < BNODES) off[tid] += v;
        __syncthreads();
    }
    if (tid < BNODES) {
        boff[b * BNODES + tid] = off[tid] - cnt[tid];   // exclusive, ALWAYS written
        const int node = n0 + tid;
        if (node < N) dinv[node] = rsqrtf((float)(cnt[tid] + 1));   // +1 self-loop
    }
}

// ---- 3. GEMM via MFMA: y_bf16 = bf16((z @ W) * dinv[row]) ----
__global__ void gemm_mfma(const float* __restrict__ z,
                          const unsigned short* __restrict__ wfrag,
                          const float* __restrict__ dinv,
                          unsigned short* __restrict__ y, int N) {
    const int lane = threadIdx.x & 63;
    const int wid  = threadIdx.x >> 6;
    const int row0 = blockIdx.x * 64 + wid * 16;

    bf16x8 bfr[4][4];                                 // [ntile][kk]
#pragma unroll
    for (int nt = 0; nt < 4; ++nt)
#pragma unroll
        for (int kk = 0; kk < 4; ++kk)
            bfr[nt][kk] = *(const bf16x8*)&wfrag[(((nt * 4 + kk) * 64) + lane) * 8];

    f32x4 acc[4];
#pragma unroll
    for (int nt = 0; nt < 4; ++nt) acc[nt] = (f32x4){0.f, 0.f, 0.f, 0.f};

    const int arow = row0 + (lane & 15);
    const int zrow = (arow < N) ? arow : (N - 1);     // clamp: tail lanes read valid mem
    const int sub  = lane >> 4;
    const float* zr = z + (size_t)zrow * IN_CH + sub * 8;

#pragma unroll
    for (int kk = 0; kk < 4; ++kk) {
        float4 f0 = *(const float4*)(zr + kk * 32);
        float4 f1 = *(const float4*)(zr + kk * 32 + 4);
        bf16x8 a;
        a[0] = (short)f2bf(f0.x); a[1] = (short)f2bf(f0.y);
        a[2] = (short)f2bf(f0.z); a[3] = (short)f2bf(f0.w);
        a[4] = (short)f2bf(f1.x); a[5] = (short)f2bf(f1.y);
        a[6] = (short)f2bf(f1.z); a[7] = (short)f2bf(f1.w);
#pragma unroll
        for (int nt = 0; nt < 4; ++nt)
            acc[nt] = __builtin_amdgcn_mfma_f32_16x16x32_bf16(a, bfr[nt][kk], acc[nt], 0, 0, 0);
    }

    // C/D layout: col = lane&15 (+16*nt), row = (lane>>4)*4 + r
    const int crow0 = row0 + sub * 4;
#pragma unroll
    for (int r = 0; r < 4; ++r) {
        int row = crow0 + r;
        if (row < N) {
            float di = dinv[row];
#pragma unroll
            for (int nt = 0; nt < 4; ++nt)
                y[(size_t)row * OUT_CH + nt * 16 + (lane & 15)] = f2bf(acc[nt][r] * di);
        }
    }
}

// ---- 4. LDS scatter-sort (offsets precomputed) + two-pass channel-split gather ----
__global__ __launch_bounds__(512) void sort_gather(const unsigned int* __restrict__ ebuf,
                                                   const int* __restrict__ gctr,
                                                   const int* __restrict__ boff,
                                                   const unsigned int* __restrict__ y32,
                                                   const float* __restrict__ dinv,
                                                   const float* __restrict__ bias,
                                                   float* __restrict__ out, int N) {
    __shared__ unsigned short scol[CAP];    // 3 KB
    __shared__ int off_s[BNODES];
    __shared__ int cur[BNODES];
    __shared__ int ecnt_s;
    const int b = blockIdx.x;
    const int n0 = b << CSHIFT;
    const int tid = threadIdx.x;

    if (tid < BNODES) {
        int o = boff[b * BNODES + tid];
        off_s[tid] = o;
        cur[tid] = o;
    }
    if (tid == 0) {
        int s = 0;
#pragma unroll
        for (int gi = 0; gi < NGRP; ++gi) s += min(gctr[b * NGRP + gi], CAPC);
        ecnt_s = s;
    }
    __syncthreads();

    // scatter: scol sorted by dst-rel (8 contiguous chunk streams)
#pragma unroll
    for (int gi = 0; gi < NGRP; ++gi) {
        const int ec = min(gctr[b * NGRP + gi], CAPC);
        const unsigned int* eb = ebuf + ((size_t)b * NGRP + gi) * CAPC;
        for (int i = tid; i < ec; i += 512) {
            unsigned int p = eb[i];
            int rel = (int)(p >> 16) - n0;
            int slot = atomicAdd(&cur[rel], 1);
            if (slot < CAP) scol[slot] = (unsigned short)(p & 0xFFFFu);
        }
    }
    __syncthreads();
    const int ecnt = ecnt_s;

    const int lane = tid & 63;
    const int w = tid >> 6;                  // 8 waves
    const int q = lane >> 4;                 // quarter 0..3
    const int c4 = lane & 15;                // u32 index within 16-u32 half-row

#pragma unroll
    for (int rnd = 0; rnd < 2; ++rnd) {
        const int nrel = rnd * 32 + w * 4 + q;      // 0..63
        const int node = n0 + nrel;
        const bool valid = node < N;
        const int jbeg = off_s[nrel];
        const int jend = (nrel < BNODES - 1) ? off_s[nrel + 1] : ecnt;
        const float di = valid ? dinv[node] : 0.f;

#pragma unroll
        for (int pass = 0; pass < 2; ++pass) {
            const size_t hbase = (size_t)pass * 16 + c4;
            float accLo = 0.f, accHi = 0.f;
            if (valid) {
                unsigned int sv = y32[(size_t)node * 32 + hbase];   // self-loop term
                accLo = bf2f((unsigned short)(sv & 0xFFFFu));
                accHi = bf2f((unsigned short)(sv >> 16));
            }

            for (int j = jbeg; j < jend; j += 8) {
                unsigned int v[8]; bool m[8];
#pragma unroll
                for (int t = 0; t < 8; ++t) {
                    int jj = j + t;
                    m[t] = jj < jend;
                    int s = scol[m[t] ? jj : (jend - 1)];
                    v[t] = y32[(size_t)s * 32 + hbase];
                }
#pragma unroll
                for (int t = 0; t < 8; ++t) {
                    if (m[t]) {
                        accLo += bf2f((unsigned short)(v[t] & 0xFFFFu));
                        accHi += bf2f((unsigned short)(v[t] >> 16));
                    }
                }
            }

            if (valid) {
                const int ch = pass * 32 + c4 * 2;
                float2 bv = *(const float2*)&bias[ch];
                float2 o2;
                o2.x = fmaxf(fmaf(accLo, di, bv.x), 0.f);
                o2.y = fmaxf(fmaf(accHi, di, bv.y), 0.f);
                *(float2*)&out[(size_t)node * OUT_CH + ch] = o2;
            }
        }
    }
}

extern "C" void kernel_launch(void* const* d_in, const int* in_sizes, int n_in,
                              void* d_out, int out_size, void* d_ws, size_t ws_size,
                              hipStream_t stream) {
    const float* z  = (const float*)d_in[0];
    const int*   ei = (const int*)d_in[1];     // int32 [2, E]
    const float* W  = (const float*)d_in[2];
    const float* b  = (const float*)d_in[3];
    float*       out = (float*)d_out;

    const int N = in_sizes[0] / IN_CH;        // 50000 (< 65536 -> 16-bit packable)
    const int E = in_sizes[1] / 2;            // 800000
    const int NC = (N + BNODES - 1) >> CSHIFT;   // 782 buckets

    // ws: y_bf16 [N*64 u16] | ebuf [NC*NGRP*CAPC u32] | dinv [N f] | boff [NC*64 i]
    //     | gctr [NC*NGRP i] | wfrag [8192 u16]
    unsigned short* y     = (unsigned short*)d_ws;
    unsigned int*   ebuf  = (unsigned int*)(y + (size_t)N * OUT_CH);
    float*          dinv  = (float*)(ebuf + (size_t)NC * NGRP * CAPC);
    int*            boff  = (int*)(dinv + N);
    int*            gctr  = boff + (size_t)NC * BNODES;
    unsigned short* wfrag = (unsigned short*)(((uintptr_t)(gctr + NC * NGRP) + 15) & ~(uintptr_t)15);

    hipMemsetAsync(gctr, 0, (size_t)NC * NGRP * sizeof(int), stream);

    const int binBlocks = (E + 256 * BIN_EPT - 1) / (256 * BIN_EPT);   // 391

    bin_edges   <<<binBlocks, 256, 0, stream>>>(ei, gctr, ebuf, E, NC);
    degree_wfrag<<<NC + 1, 256, 0, stream>>>(ebuf, gctr, dinv, boff, N, NC, W, wfrag);
    gemm_mfma   <<<(N + 63) / 64, 256, 0, stream>>>(z, wfrag, dinv, y, N);
    sort_gather <<<NC, 512, 0, stream>>>(ebuf, gctr, boff, (const unsigned int*)y,
                                         dinv, b, out, N);
}

// Round 16
// 71.569 us; speedup vs baseline: 1.0898x; 1.0898x over previous
//
#include <hip/hip_runtime.h>
#include <hip/hip_bf16.h>

#define IN_CH 128
#define OUT_CH 64

#define CSHIFT 6                 // bucket = 64 dst nodes
#define BNODES 64
#define NCMAX 1024               // LDS counter bound (NC = 782 for N=50000)
#define CAP 1536                 // per-bucket capacity (mean ~1023, sigma ~32 -> +16 sigma)
#define BIN_EPT 8                // edges per thread in binning kernel

typedef __attribute__((ext_vector_type(8))) short bf16x8;
typedef __attribute__((ext_vector_type(4))) float f32x4;

// compiler-friendly f32->bf16 (RNE): hipcc fuses pairs into v_cvt_pk_bf16_f32
__device__ inline short f2bfs(float x) {
    __hip_bfloat16 h = __float2bfloat16(x);
    return __builtin_bit_cast(short, h);
}
__device__ inline float bf2f(unsigned short h) {
    unsigned int u = ((unsigned int)h) << 16;
    return __builtin_bit_cast(float, u);
}

// ---- 1. bin edges into fixed-capacity buckets, packed (dst<<16)|src ----
// int4-vectorized ei loads; per-block LDS counting; ONE global atomic per
// (block,bucket) reserves a dense run.
__global__ void bin_edges(const int* __restrict__ ei, int* __restrict__ gctr,
                          unsigned int* __restrict__ ebuf, int E, int NC) {
    __shared__ int cnt[NCMAX];
    __shared__ int gbase[NCMAX];
    for (int i = threadIdx.x; i < NC; i += blockDim.x) cnt[i] = 0;
    __syncthreads();

    unsigned int pk[BIN_EPT];
    int bk[BIN_EPT];
    const int g0 = (blockIdx.x * blockDim.x + threadIdx.x) * BIN_EPT;

    if (g0 + BIN_EPT <= E) {
        int4 s0 = *(const int4*)(ei + g0);
        int4 s1 = *(const int4*)(ei + g0 + 4);
        int4 d0 = *(const int4*)(ei + E + g0);
        int4 d1 = *(const int4*)(ei + E + g0 + 4);
        int ss[BIN_EPT] = {s0.x, s0.y, s0.z, s0.w, s1.x, s1.y, s1.z, s1.w};
        int dd[BIN_EPT] = {d0.x, d0.y, d0.z, d0.w, d1.x, d1.y, d1.z, d1.w};
#pragma unroll
        for (int k = 0; k < BIN_EPT; ++k) {
            pk[k] = ((unsigned int)dd[k] << 16) | (unsigned int)ss[k];
            bk[k] = dd[k] >> CSHIFT;
            atomicAdd(&cnt[bk[k]], 1);
        }
    } else {
#pragma unroll
        for (int k = 0; k < BIN_EPT; ++k) {
            int e = g0 + k;
            if (e < E) {
                int s = ei[e];
                int d = ei[E + e];
                pk[k] = ((unsigned int)d << 16) | (unsigned int)s;
                bk[k] = d >> CSHIFT;
                atomicAdd(&cnt[bk[k]], 1);
            } else bk[k] = -1;
        }
    }
    __syncthreads();
    for (int i = threadIdx.x; i < NC; i += blockDim.x) {
        int c = cnt[i];
        gbase[i] = c ? atomicAdd(&gctr[i], c) : 0;
    }
    __syncthreads();
    for (int i = threadIdx.x; i < NC; i += blockDim.x) cnt[i] = 0;  // reuse as local cursor
    __syncthreads();
#pragma unroll
    for (int k = 0; k < BIN_EPT; ++k) {
        if (bk[k] >= 0) {
            int o = gbase[bk[k]] + atomicAdd(&cnt[bk[k]], 1);
            if (o < CAP)   // overflow guard (statistically unreachable here)
                ebuf[(size_t)bk[k] * CAP + o] = pk[k];
        }
    }
}

// ---- 2. fused: degree->dinv + within-bucket exclusive offsets (blocks 0..NC-1),
//      W-fragment prep (block NC) ----
__global__ void degree_wfrag(const unsigned int* __restrict__ ebuf,
                             const int* __restrict__ gctr,
                             float* __restrict__ dinv, int* __restrict__ boff,
                             int N, int NC,
                             const float* __restrict__ W,
                             unsigned short* __restrict__ wf) {
    const int b = blockIdx.x;
    if (b == NC) {   // W fragment pre-pack: wf[((nt*4+kk)*64+lane)*8+j]
        for (int i = threadIdx.x; i < 4 * 4 * 64 * 8; i += blockDim.x) {
            int j    = i & 7;
            int lane = (i >> 3) & 63;
            int kk   = (i >> 9) & 3;
            int nt   = i >> 11;
            int k = kk * 32 + ((lane >> 4) & 3) * 8 + j;
            int n = nt * 16 + (lane & 15);
            wf[i] = (unsigned short)f2bfs(W[k * OUT_CH + n]);
        }
        return;
    }
    __shared__ int cnt[BNODES];
    __shared__ int off[BNODES];
    const int tid = threadIdx.x;
    const int n0 = b << CSHIFT;
    if (tid < BNODES) cnt[tid] = 0;
    __syncthreads();
    const int ecnt = min(gctr[b], CAP);
    const unsigned int* eb = ebuf + (size_t)b * CAP;
    for (int i = tid; i < ecnt; i += blockDim.x)
        atomicAdd(&cnt[(int)(eb[i] >> 16) - n0], 1);
    __syncthreads();
    if (tid < BNODES) off[tid] = cnt[tid];
    __syncthreads();
    for (int o = 1; o < BNODES; o <<= 1) {
        int v = 0;
        if (tid < BNODES && tid >= o) v = off[tid - o];
        __syncthreads();
        if (tid < BNODES) off[tid] += v;
        __syncthreads();
    }
    if (tid < BNODES) {
        boff[b * BNODES + tid] = off[tid] - cnt[tid];   // exclusive, ALWAYS written
        const int node = n0 + tid;
        if (node < N) dinv[node] = rsqrtf((float)(cnt[tid] + 1));   // +1 self-loop
    }
}

// ---- 3. GEMM via MFMA: y_bf16 = bf16((z @ W) * dinv[row]) ----
// Conversions use __float2bfloat16 so hipcc emits v_cvt_pk_bf16_f32 pairs
// (manual bit-twiddle RNE blocked the pattern match and left gemm VALU-bound).
__global__ void gemm_mfma(const float* __restrict__ z,
                          const unsigned short* __restrict__ wfrag,
                          const float* __restrict__ dinv,
                          unsigned short* __restrict__ y, int N) {
    const int lane = threadIdx.x & 63;
    const int wid  = threadIdx.x >> 6;
    const int row0 = blockIdx.x * 64 + wid * 16;

    bf16x8 bfr[4][4];                                 // [ntile][kk]
#pragma unroll
    for (int nt = 0; nt < 4; ++nt)
#pragma unroll
        for (int kk = 0; kk < 4; ++kk)
            bfr[nt][kk] = *(const bf16x8*)&wfrag[(((nt * 4 + kk) * 64) + lane) * 8];

    f32x4 acc[4];
#pragma unroll
    for (int nt = 0; nt < 4; ++nt) acc[nt] = (f32x4){0.f, 0.f, 0.f, 0.f};

    const int arow = row0 + (lane & 15);
    const int zrow = (arow < N) ? arow : (N - 1);     // clamp: tail lanes read valid mem
    const int sub  = lane >> 4;
    const float* zr = z + (size_t)zrow * IN_CH + sub * 8;

#pragma unroll
    for (int kk = 0; kk < 4; ++kk) {
        float4 f0 = *(const float4*)(zr + kk * 32);
        float4 f1 = *(const float4*)(zr + kk * 32 + 4);
        bf16x8 a;
        a[0] = f2bfs(f0.x); a[1] = f2bfs(f0.y);
        a[2] = f2bfs(f0.z); a[3] = f2bfs(f0.w);
        a[4] = f2bfs(f1.x); a[5] = f2bfs(f1.y);
        a[6] = f2bfs(f1.z); a[7] = f2bfs(f1.w);
#pragma unroll
        for (int nt = 0; nt < 4; ++nt)
            acc[nt] = __builtin_amdgcn_mfma_f32_16x16x32_bf16(a, bfr[nt][kk], acc[nt], 0, 0, 0);
    }

    // C/D layout: col = lane&15 (+16*nt), row = (lane>>4)*4 + r
    const int crow0 = row0 + sub * 4;
#pragma unroll
    for (int r = 0; r < 4; ++r) {
        int row = crow0 + r;
        if (row < N) {
            float di = dinv[row];
#pragma unroll
            for (int nt = 0; nt < 4; ++nt)
                y[(size_t)row * OUT_CH + nt * 16 + (lane & 15)] =
                    (unsigned short)f2bfs(acc[nt][r] * di);
        }
    }
}

// ---- 4. fused LDS counting-sort + node-parallel gather (masked 8-wide bursts) ----
__global__ __launch_bounds__(512) void sort_gather(const unsigned int* __restrict__ ebuf,
                                                   const int* __restrict__ gctr,
                                                   const int* __restrict__ boff,
                                                   const unsigned int* __restrict__ y2,
                                                   const float* __restrict__ dinv,
                                                   const float* __restrict__ bias,
                                                   float* __restrict__ out, int N) {
    __shared__ unsigned short scol[CAP];    // 3 KB
    __shared__ int off_s[BNODES];
    __shared__ int cur[BNODES];
    const int b = blockIdx.x;
    const int n0 = b << CSHIFT;
    const int tid = threadIdx.x;
    const int ecnt = min(gctr[b], CAP);
    const unsigned int* eb = ebuf + (size_t)b * CAP;

    if (tid < BNODES) {
        int o = boff[b * BNODES + tid];
        off_s[tid] = o;
        cur[tid] = o;
    }
    __syncthreads();

    // scatter: scol sorted by dst-rel (single pass over global edges)
    for (int i = tid; i < ecnt; i += 512) {
        unsigned int p = eb[i];
        int rel = (int)(p >> 16) - n0;
        int slot = atomicAdd(&cur[rel], 1);
        scol[slot] = (unsigned short)(p & 0xFFFFu);
    }
    __syncthreads();

    const int lane = tid & 63;
    const int w = tid >> 6;                  // 8 waves
    const int half = lane >> 5;
    const int c2 = lane & 31;
    const float2 bv = *(const float2*)&bias[c2 * 2];

#pragma unroll
    for (int rnd = 0; rnd < 4; ++rnd) {
        const int nrel = rnd * 16 + w * 2 + half;   // 0..63
        const int node = n0 + nrel;
        const bool valid = node < N;
        int jbeg = valid ? off_s[nrel] : 0;
        int cend = valid ? ((nrel < BNODES - 1) ? off_s[nrel + 1] : ecnt) : 0;

        float accLo = 0.f, accHi = 0.f;
        if (valid) {
            unsigned int sv = y2[(size_t)node * 32 + c2];   // self-loop term
            accLo = bf2f((unsigned short)(sv & 0xFFFFu));
            accHi = bf2f((unsigned short)(sv >> 16));
        }

        // masked 8-wide bursts: full neighbor list pipelined, no serial tail
        for (int j = jbeg; j < cend; j += 8) {
            unsigned int v[8]; bool m[8];
#pragma unroll
            for (int t = 0; t < 8; ++t) {
                int jj = j + t;
                m[t] = jj < cend;
                int s = scol[m[t] ? jj : (cend - 1)];
                v[t] = y2[(size_t)s * 32 + c2];
            }
#pragma unroll
            for (int t = 0; t < 8; ++t) {
                if (m[t]) {
                    accLo += bf2f((unsigned short)(v[t] & 0xFFFFu));
                    accHi += bf2f((unsigned short)(v[t] >> 16));
                }
            }
        }

        if (valid) {
            float di = dinv[node];
            float2 o2;
            o2.x = fmaxf(fmaf(accLo, di, bv.x), 0.f);
            o2.y = fmaxf(fmaf(accHi, di, bv.y), 0.f);
            *(float2*)&out[(size_t)node * OUT_CH + c2 * 2] = o2;
        }
    }
}

extern "C" void kernel_launch(void* const* d_in, const int* in_sizes, int n_in,
                              void* d_out, int out_size, void* d_ws, size_t ws_size,
                              hipStream_t stream) {
    const float* z  = (const float*)d_in[0];
    const int*   ei = (const int*)d_in[1];     // int32 [2, E]
    const float* W  = (const float*)d_in[2];
    const float* b  = (const float*)d_in[3];
    float*       out = (float*)d_out;

    const int N = in_sizes[0] / IN_CH;        // 50000 (< 65536 -> 16-bit packable)
    const int E = in_sizes[1] / 2;            // 800000
    const int NC = (N + BNODES - 1) >> CSHIFT;   // 782 buckets

    // ws: y_bf16 [N*64 u16] | ebuf [NC*CAP u32] | dinv [N f] | boff [NC*64 i]
    //     | gctr [NC] | wfrag [8192 u16]
    unsigned short* y     = (unsigned short*)d_ws;
    unsigned int*   ebuf  = (unsigned int*)(y + (size_t)N * OUT_CH);
    float*          dinv  = (float*)(ebuf + (size_t)NC * CAP);
    int*            boff  = (int*)(dinv + N);
    int*            gctr  = boff + (size_t)NC * BNODES;
    unsigned short* wfrag = (unsigned short*)(((uintptr_t)(gctr + NC) + 15) & ~(uintptr_t)15);

    hipMemsetAsync(gctr, 0, (size_t)NC * sizeof(int), stream);

    const int binBlocks = (E + 256 * BIN_EPT - 1) / (256 * BIN_EPT);   // 391

    bin_edges   <<<binBlocks, 256, 0, stream>>>(ei, gctr, ebuf, E, NC);
    degree_wfrag<<<NC + 1, 256, 0, stream>>>(ebuf, gctr, dinv, boff, N, NC, W, wfrag);
    gemm_mfma   <<<(N + 63) / 64, 256, 0, stream>>>(z, wfrag, dinv, y, N);
    sort_gather <<<NC, 512, 0, stream>>>(ebuf, gctr, boff, (const unsigned int*)y,
                                         dinv, b, out, N);
}

// Round 17
// 66.364 us; speedup vs baseline: 1.1752x; 1.0784x over previous
//
#include <hip/hip_runtime.h>
#include <hip/hip_bf16.h>

#define IN_CH 128
#define OUT_CH 64

#define CSHIFT 6                 // bucket = 64 dst nodes
#define BNODES 64
#define NCMAX 1024               // LDS counter bound (NC = 782 for N=50000)
#define CAP 1536                 // per-bucket capacity (mean ~1023, sigma ~32 -> +16 sigma)
#define BIN_EPT 8                // edges per thread in binning kernel

typedef __attribute__((ext_vector_type(8))) short bf16x8;
typedef __attribute__((ext_vector_type(4))) float f32x4;

// compiler-friendly f32->bf16 (RNE): hipcc fuses pairs into v_cvt_pk_bf16_f32
__device__ inline short f2bfs(float x) {
    __hip_bfloat16 h = __float2bfloat16(x);
    return __builtin_bit_cast(short, h);
}
__device__ inline float bf2f(unsigned short h) {
    unsigned int u = ((unsigned int)h) << 16;
    return __builtin_bit_cast(float, u);
}

// ---- 1. bin edges into fixed-capacity buckets (blocks 0..nbin-1);
//      W-fragment prep (block nbin) ----
__global__ void bin_edges(const int* __restrict__ ei, int* __restrict__ gctr,
                          unsigned int* __restrict__ ebuf, int E, int NC, int nbin,
                          const float* __restrict__ W, unsigned short* __restrict__ wf) {
    if (blockIdx.x == (unsigned)nbin) {   // wf[((nt*4+kk)*64+lane)*8+j]
        for (int i = threadIdx.x; i < 4 * 4 * 64 * 8; i += blockDim.x) {
            int j    = i & 7;
            int lane = (i >> 3) & 63;
            int kk   = (i >> 9) & 3;
            int nt   = i >> 11;
            int k = kk * 32 + ((lane >> 4) & 3) * 8 + j;
            int n = nt * 16 + (lane & 15);
            wf[i] = (unsigned short)f2bfs(W[k * OUT_CH + n]);
        }
        return;
    }
    __shared__ int cnt[NCMAX];
    __shared__ int gbase[NCMAX];
    for (int i = threadIdx.x; i < NC; i += blockDim.x) cnt[i] = 0;
    __syncthreads();

    unsigned int pk[BIN_EPT];
    int bk[BIN_EPT];
    const int g0 = (blockIdx.x * blockDim.x + threadIdx.x) * BIN_EPT;

    if (g0 + BIN_EPT <= E) {
        int4 s0 = *(const int4*)(ei + g0);
        int4 s1 = *(const int4*)(ei + g0 + 4);
        int4 d0 = *(const int4*)(ei + E + g0);
        int4 d1 = *(const int4*)(ei + E + g0 + 4);
        int ss[BIN_EPT] = {s0.x, s0.y, s0.z, s0.w, s1.x, s1.y, s1.z, s1.w};
        int dd[BIN_EPT] = {d0.x, d0.y, d0.z, d0.w, d1.x, d1.y, d1.z, d1.w};
#pragma unroll
        for (int k = 0; k < BIN_EPT; ++k) {
            pk[k] = ((unsigned int)dd[k] << 16) | (unsigned int)ss[k];
            bk[k] = dd[k] >> CSHIFT;
            atomicAdd(&cnt[bk[k]], 1);
        }
    } else {
#pragma unroll
        for (int k = 0; k < BIN_EPT; ++k) {
            int e = g0 + k;
            if (e < E) {
                int s = ei[e];
                int d = ei[E + e];
                pk[k] = ((unsigned int)d << 16) | (unsigned int)s;
                bk[k] = d >> CSHIFT;
                atomicAdd(&cnt[bk[k]], 1);
            } else bk[k] = -1;
        }
    }
    __syncthreads();
    for (int i = threadIdx.x; i < NC; i += blockDim.x) {
        int c = cnt[i];
        gbase[i] = c ? atomicAdd(&gctr[i], c) : 0;
    }
    __syncthreads();
    for (int i = threadIdx.x; i < NC; i += blockDim.x) cnt[i] = 0;  // reuse as local cursor
    __syncthreads();
#pragma unroll
    for (int k = 0; k < BIN_EPT; ++k) {
        if (bk[k] >= 0) {
            int o = gbase[bk[k]] + atomicAdd(&cnt[bk[k]], 1);
            if (o < CAP)   // overflow guard (statistically unreachable here)
                ebuf[(size_t)bk[k] * CAP + o] = pk[k];
        }
    }
}

// ---- 2. fused: LDS count+scan+sort (-> boff, gscol) + MFMA GEMM for the same
//      64 rows. Bucket b == gemm row-block b, so degree work overlaps GEMM
//      across blocks and dinv never round-trips through global. ----
__global__ __launch_bounds__(256) void sort_gemm(const unsigned int* __restrict__ ebuf,
                                                 const int* __restrict__ gctr,
                                                 const float* __restrict__ z,
                                                 const unsigned short* __restrict__ wfrag,
                                                 int* __restrict__ boff,
                                                 unsigned short* __restrict__ gscol,
                                                 unsigned short* __restrict__ y, int N) {
    __shared__ unsigned int epk[CAP];        // 6 KB
    __shared__ unsigned short scolL[CAP];    // 3 KB
    __shared__ int cnt[BNODES];
    __shared__ int off[BNODES];
    __shared__ float dinvL[BNODES];
    const int b = blockIdx.x;
    const int tid = threadIdx.x;
    const int n0 = b << CSHIFT;
    const int ecnt = min(gctr[b], CAP);
    const unsigned int* eb = ebuf + (size_t)b * CAP;

    if (tid < BNODES) cnt[tid] = 0;
    __syncthreads();
    for (int i = tid; i < ecnt; i += 256) {
        unsigned int p = eb[i];
        epk[i] = p;
        atomicAdd(&cnt[(int)(p >> 16) - n0], 1);
    }
    __syncthreads();

    int deg = 0;
    if (tid < BNODES) { deg = cnt[tid]; off[tid] = deg; }
    __syncthreads();
    for (int o = 1; o < BNODES; o <<= 1) {
        int v = (tid < BNODES && tid >= o) ? off[tid - o] : 0;
        __syncthreads();
        if (tid < BNODES) off[tid] += v;
        __syncthreads();
    }
    if (tid < BNODES) {
        int ex = off[tid] - deg;                 // exclusive offset
        boff[b * BNODES + tid] = ex;
        cnt[tid] = ex;                           // cursor
        dinvL[tid] = rsqrtf((float)(deg + 1));   // +1 self-loop
    }
    __syncthreads();

    for (int i = tid; i < ecnt; i += 256) {      // scatter-sort in LDS
        unsigned int p = epk[i];
        int rel = (int)(p >> 16) - n0;
        int slot = atomicAdd(&cnt[rel], 1);
        scolL[slot] = (unsigned short)(p & 0xFFFFu);
    }
    __syncthreads();
    for (int i = tid; i < ecnt; i += 256)        // dense single-writer store
        gscol[(size_t)b * CAP + i] = scolL[i];

    // ---- GEMM: y[n0..n0+63] = bf16((z @ W) * dinvL) ----
    const int lane = tid & 63;
    const int wid  = tid >> 6;
    const int row0 = n0 + wid * 16;

    bf16x8 bfr[4][4];                                 // [ntile][kk]
#pragma unroll
    for (int nt = 0; nt < 4; ++nt)
#pragma unroll
        for (int kk = 0; kk < 4; ++kk)
            bfr[nt][kk] = *(const bf16x8*)&wfrag[(((nt * 4 + kk) * 64) + lane) * 8];

    f32x4 acc[4];
#pragma unroll
    for (int nt = 0; nt < 4; ++nt) acc[nt] = (f32x4){0.f, 0.f, 0.f, 0.f};

    const int arow = row0 + (lane & 15);
    const int zrow = (arow < N) ? arow : (N - 1);     // clamp: tail lanes read valid mem
    const int sub  = lane >> 4;
    const float* zr = z + (size_t)zrow * IN_CH + sub * 8;

#pragma unroll
    for (int kk = 0; kk < 4; ++kk) {
        float4 f0 = *(const float4*)(zr + kk * 32);
        float4 f1 = *(const float4*)(zr + kk * 32 + 4);
        bf16x8 a;
        a[0] = f2bfs(f0.x); a[1] = f2bfs(f0.y);
        a[2] = f2bfs(f0.z); a[3] = f2bfs(f0.w);
        a[4] = f2bfs(f1.x); a[5] = f2bfs(f1.y);
        a[6] = f2bfs(f1.z); a[7] = f2bfs(f1.w);
#pragma unroll
        for (int nt = 0; nt < 4; ++nt)
            acc[nt] = __builtin_amdgcn_mfma_f32_16x16x32_bf16(a, bfr[nt][kk], acc[nt], 0, 0, 0);
    }

    // C/D layout: col = lane&15 (+16*nt), row = (lane>>4)*4 + r
    const int rrel0 = wid * 16 + sub * 4;
#pragma unroll
    for (int r = 0; r < 4; ++r) {
        int row = n0 + rrel0 + r;
        if (row < N) {
            float di = dinvL[rrel0 + r];
#pragma unroll
            for (int nt = 0; nt < 4; ++nt)
                y[(size_t)row * OUT_CH + nt * 16 + (lane & 15)] =
                    (unsigned short)f2bfs(acc[nt][r] * di);
        }
    }
}

// ---- 3. pure gather: stage pre-sorted cols, masked 8-wide bursts;
//      dinv recomputed from range width (no global dinv). ----
__global__ __launch_bounds__(512) void gather(const int* __restrict__ gctr,
                                              const int* __restrict__ boff,
                                              const unsigned short* __restrict__ gscol,
                                              const unsigned int* __restrict__ y2,
                                              const float* __restrict__ bias,
                                              float* __restrict__ out, int N) {
    __shared__ unsigned short scol[CAP];    // 3 KB
    __shared__ int off_s[BNODES + 1];
    const int b = blockIdx.x;
    const int n0 = b << CSHIFT;
    const int tid = threadIdx.x;
    const int ecnt = min(gctr[b], CAP);

    if (tid < BNODES) off_s[tid] = boff[b * BNODES + tid];
    if (tid == 0) off_s[BNODES] = ecnt;
    __syncthreads();
    {   // contiguous u32 copy of sorted cols
        const unsigned int* gs32 = (const unsigned int*)(gscol + (size_t)b * CAP);
        unsigned int* sc32 = (unsigned int*)scol;
        for (int i = tid; i < (ecnt + 1) / 2; i += 512) sc32[i] = gs32[i];
    }
    __syncthreads();

    const int lane = tid & 63;
    const int w = tid >> 6;                  // 8 waves
    const int half = lane >> 5;
    const int c2 = lane & 31;
    const float2 bv = *(const float2*)&bias[c2 * 2];

#pragma unroll
    for (int rnd = 0; rnd < 4; ++rnd) {
        const int nrel = rnd * 16 + w * 2 + half;   // 0..63
        const int node = n0 + nrel;
        const bool valid = node < N;
        int jbeg = valid ? off_s[nrel] : 0;
        int cend = valid ? off_s[nrel + 1] : 0;
        const float di = rsqrtf((float)(cend - jbeg + 1));   // dinv[dst]

        float accLo = 0.f, accHi = 0.f;
        if (valid) {
            unsigned int sv = y2[(size_t)node * 32 + c2];   // self-loop term
            accLo = bf2f((unsigned short)(sv & 0xFFFFu));
            accHi = bf2f((unsigned short)(sv >> 16));
        }

        for (int j = jbeg; j < cend; j += 8) {   // masked 8-wide bursts
            unsigned int v[8]; bool m[8];
#pragma unroll
            for (int t = 0; t < 8; ++t) {
                int jj = j + t;
                m[t] = jj < cend;
                int s = scol[m[t] ? jj : (cend - 1)];
                v[t] = y2[(size_t)s * 32 + c2];
            }
#pragma unroll
            for (int t = 0; t < 8; ++t) {
                if (m[t]) {
                    accLo += bf2f((unsigned short)(v[t] & 0xFFFFu));
                    accHi += bf2f((unsigned short)(v[t] >> 16));
                }
            }
        }

        if (valid) {
            float2 o2;
            o2.x = fmaxf(fmaf(accLo, di, bv.x), 0.f);
            o2.y = fmaxf(fmaf(accHi, di, bv.y), 0.f);
            *(float2*)&out[(size_t)node * OUT_CH + c2 * 2] = o2;
        }
    }
}

extern "C" void kernel_launch(void* const* d_in, const int* in_sizes, int n_in,
                              void* d_out, int out_size, void* d_ws, size_t ws_size,
                              hipStream_t stream) {
    const float* z  = (const float*)d_in[0];
    const int*   ei = (const int*)d_in[1];     // int32 [2, E]
    const float* W  = (const float*)d_in[2];
    const float* b  = (const float*)d_in[3];
    float*       out = (float*)d_out;

    const int N = in_sizes[0] / IN_CH;        // 50000 (< 65536 -> 16-bit packable)
    const int E = in_sizes[1] / 2;            // 800000
    const int NC = (N + BNODES - 1) >> CSHIFT;   // 782 buckets

    // ws: y_bf16 [N*64 u16] | ebuf [NC*CAP u32] | gscol [NC*CAP u16] | boff [NC*64 i]
    //     | gctr [NC] | wfrag [8192 u16]
    unsigned short* y     = (unsigned short*)d_ws;
    unsigned int*   ebuf  = (unsigned int*)(y + (size_t)N * OUT_CH);
    unsigned short* gscol = (unsigned short*)(ebuf + (size_t)NC * CAP);
    int*            boff  = (int*)(gscol + (size_t)NC * CAP);
    int*            gctr  = boff + (size_t)NC * BNODES;
    unsigned short* wfrag = (unsigned short*)(((uintptr_t)(gctr + NC) + 15) & ~(uintptr_t)15);

    hipMemsetAsync(gctr, 0, (size_t)NC * sizeof(int), stream);

    const int binBlocks = (E + 256 * BIN_EPT - 1) / (256 * BIN_EPT);   // 391

    bin_edges<<<binBlocks + 1, 256, 0, stream>>>(ei, gctr, ebuf, E, NC, binBlocks, W, wfrag);
    sort_gemm<<<NC, 256, 0, stream>>>(ebuf, gctr, z, wfrag, boff, gscol, y, N);
    gather   <<<NC, 512, 0, stream>>>(gctr, boff, gscol, (const unsigned int*)y, b, out, N);
}